// Round 1
// baseline (4720.372 us; speedup 1.0000x reference)
//
#include <hip/hip_runtime.h>
#include <math.h>

#define CDIM 128
#define EDIM 512
#define BLK 256
#define NVEC 262144          // 8*32*32*32 vectors
#define SPATIAL 32768        // 32*32*32
#define QELEMS 33554432LL    // NVEC*CDIM

// workspace layout
struct WS {
  float  wn[EDIM];     // ||e||^2 per embedding
  int    counts[EDIM]; // histogram of argmin indices
  double lossAcc;      // sum of (q-x)^2 over all elements
};

// ---- pre-pass: compute weight norms, zero accumulators (ws is poisoned each call)
__global__ __launch_bounds__(512) void vq_pre(const float* __restrict__ wt, WS* __restrict__ ws) {
  int t = threadIdx.x;           // one thread per embedding, 512 threads
  const float* w = wt + (size_t)t * CDIM;
  float a0 = 0.f, a1 = 0.f, a2 = 0.f, a3 = 0.f;
#pragma unroll
  for (int c = 0; c < CDIM; c += 4) {
    a0 = fmaf(w[c + 0], w[c + 0], a0);
    a1 = fmaf(w[c + 1], w[c + 1], a1);
    a2 = fmaf(w[c + 2], w[c + 2], a2);
    a3 = fmaf(w[c + 3], w[c + 3], a3);
  }
  ws->wn[t] = (a0 + a1) + (a2 + a3);
  ws->counts[t] = 0;
  if (t == 0) ws->lossAcc = 0.0;
}

// ---- main: argmin + out_q + encodings + loss partials + histogram
__global__ __launch_bounds__(BLK) void vq_main(const float* __restrict__ in,
                                               const float* __restrict__ wt,
                                               WS* __restrict__ ws,
                                               float* __restrict__ out_q,
                                               float* __restrict__ enc) {
  __shared__ float  wn_l[EDIM];
  __shared__ int    hist[EDIM];
  __shared__ int    sIdx[BLK];
  __shared__ double lred[BLK];

  const int tid = threadIdx.x;
  for (int e = tid; e < EDIM; e += BLK) {
    wn_l[e] = ws->wn[e];
    hist[e] = 0;
  }
  __syncthreads();

  const int n = blockIdx.x * BLK + tid;     // vector index; lanes have consecutive spatial pos
  const int b = n >> 15;                    // batch
  const int s = n & (SPATIAL - 1);          // d*h*w flat
  const float* xp = in + (size_t)b * CDIM * SPATIAL + s;

  // load the 128-dim vector into registers (coalesced per channel)
  float x[CDIM];
#pragma unroll
  for (int c = 0; c < CDIM; ++c) x[c] = xp[(size_t)c * SPATIAL];

  // fp32 scoring pass: s_e = 0.5*||e||^2 - x.e  (same argmin as full distance)
  float best = 1e30f, best2 = 1e30f;
  int bi = 0;
  for (int e = 0; e < EDIM; ++e) {
    const float* __restrict__ w = wt + (size_t)e * CDIM;  // wave-uniform -> scalar loads
    float a0 = 0.f, a1 = 0.f, a2 = 0.f, a3 = 0.f;
#pragma unroll
    for (int c = 0; c < CDIM; c += 4) {
      a0 = fmaf(w[c + 0], x[c + 0], a0);
      a1 = fmaf(w[c + 1], x[c + 1], a1);
      a2 = fmaf(w[c + 2], x[c + 2], a2);
      a3 = fmaf(w[c + 3], x[c + 3], a3);
    }
    float dot = (a0 + a1) + (a2 + a3);
    float sc = 0.5f * wn_l[e] - dot;
    if (sc < best) { best2 = best; best = sc; bi = e; }       // strict <: first-index tie-break
    else if (sc < best2) { best2 = sc; }
  }

  // ambiguous margin -> exact fp64 re-pass (rare: ~0.3% of threads)
  if (best2 - best < 2e-6f) {
    double bd = 1e300;
    int bj = 0;
    for (int e = 0; e < EDIM; ++e) {
      const float* __restrict__ w = wt + (size_t)e * CDIM;
      double acc = 0.0;
      for (int c = 0; c < CDIM; ++c) {
        double wd = (double)w[c];
        acc = fma(wd, fma(0.5, wd, -(double)x[c]), acc);   // 0.5*||e||^2 - x.e, fp64-exact
      }
      if (acc < bd) { bd = acc; bj = e; }
    }
    bi = bj;
  }

  atomicAdd(&hist[bi], 1);
  sIdx[tid] = bi;

  // gather quantized row: write out_q (transposed back) + fp64 loss partial
  const float* __restrict__ wq = wt + (size_t)bi * CDIM;
  float* oq = out_q + (size_t)b * CDIM * SPATIAL + s;
  double ls = 0.0;
#pragma unroll
  for (int c = 0; c < CDIM; ++c) {
    float qv = wq[c];
    double d = (double)qv - (double)x[c];
    ls = fma(d, d, ls);
    oq[(size_t)c * SPATIAL] = qv;                          // coalesced per channel
  }
  lred[tid] = ls;
  __syncthreads();

  // cooperative one-hot rows: block owns rows n0..n0+255, 256 float2 per row.
  // (enc base is only 8B-aligned: byte offset (2+QELEMS)*4 % 16 == 8 -> float2, not float4)
  {
    const size_t n0 = (size_t)blockIdx.x * BLK;
    float2* e2 = (float2*)enc;
    const int col = tid;                 // float2 column 0..255
    const int c0 = col * 2;
    for (int r = 0; r < BLK; ++r) {
      int idx = sIdx[r];
      float2 v;
      v.x = (idx == c0) ? 1.0f : 0.0f;
      v.y = (idx == c0 + 1) ? 1.0f : 0.0f;
      e2[(n0 + (size_t)r) * (EDIM / 2) + col] = v;
    }
  }

  // block loss reduction -> one double atomic
  for (int off = BLK / 2; off > 0; off >>= 1) {
    if (tid < off) lred[tid] += lred[tid + off];
    __syncthreads();
  }
  if (tid == 0) atomicAdd(&ws->lossAcc, lred[0]);

  // flush histogram
  for (int e = tid; e < EDIM; e += BLK) {
    int v = hist[e];
    if (v) atomicAdd(&ws->counts[e], v);
  }
}

// ---- finalize: loss scalar + perplexity from exact counts
__global__ __launch_bounds__(512) void vq_fin(const WS* __restrict__ ws, float* __restrict__ out) {
  __shared__ double red[EDIM];
  int t = threadIdx.x;
  double p = (double)ws->counts[t] * (1.0 / (double)NVEC);
  red[t] = p * log(p + 1e-10);
  __syncthreads();
  for (int off = 256; off > 0; off >>= 1) {
    if (t < off) red[t] += red[t + off];
    __syncthreads();
  }
  if (t == 0) {
    out[0] = (float)(1.25 * ws->lossAcc / (double)QELEMS);  // q_latent + 0.25*e_latent
    out[1 + QELEMS] = (float)exp(-red[0]);                  // perplexity
  }
}

extern "C" void kernel_launch(void* const* d_in, const int* in_sizes, int n_in,
                              void* d_out, int out_size, void* d_ws, size_t ws_size,
                              hipStream_t stream) {
  const float* in = (const float*)d_in[0];   // (8,128,32,32,32) fp32
  const float* wt = (const float*)d_in[1];   // (512,128) fp32
  float* out = (float*)d_out;
  WS* ws = (WS*)d_ws;

  float* out_q = out + 1;                    // 33,554,432 elems
  float* enc   = out + 2 + QELEMS;           // 134,217,728 elems

  hipLaunchKernelGGL(vq_pre,  dim3(1),          dim3(512), 0, stream, wt, ws);
  hipLaunchKernelGGL(vq_main, dim3(NVEC / BLK), dim3(BLK), 0, stream, in, wt, ws, out_q, enc);
  hipLaunchKernelGGL(vq_fin,  dim3(1),          dim3(512), 0, stream, ws, out);
}

// Round 2
// 2220.968 us; speedup vs baseline: 2.1254x; 2.1254x over previous
//
#include <hip/hip_runtime.h>
#include <math.h>

#define CDIM 128
#define EDIM 512
#define BLK 256
#define TE 64                // embeddings per LDS tile
#define NVEC 262144          // 8*32*32*32 vectors
#define SPATIAL 32768        // 32*32*32
#define QELEMS 33554432LL    // NVEC*CDIM

struct WS {
  float  wnh[EDIM];    // 0.5*||e||^2 per embedding
  int    counts[EDIM]; // histogram of argmin indices
  double lossAcc;      // sum of (q-x)^2 over all elements
};

// ---- pre-pass: half weight norms, zero accumulators (ws is poisoned each call)
__global__ __launch_bounds__(512) void vq_pre(const float* __restrict__ wt, WS* __restrict__ ws) {
  int t = threadIdx.x;
  const float* w = wt + (size_t)t * CDIM;
  float a0 = 0.f, a1 = 0.f, a2 = 0.f, a3 = 0.f;
#pragma unroll
  for (int c = 0; c < CDIM; c += 4) {
    a0 = fmaf(w[c + 0], w[c + 0], a0);
    a1 = fmaf(w[c + 1], w[c + 1], a1);
    a2 = fmaf(w[c + 2], w[c + 2], a2);
    a3 = fmaf(w[c + 3], w[c + 3], a3);
  }
  ws->wnh[t] = 0.5f * ((a0 + a1) + (a2 + a3));
  ws->counts[t] = 0;
  if (t == 0) ws->lossAcc = 0.0;
}

__device__ double score_f64(const float* __restrict__ wt, const float* x, int e) {
  const float* w = wt + (size_t)e * CDIM;
  double acc = 0.0;
  for (int c = 0; c < CDIM; ++c) {
    double wd = (double)w[c];
    acc = fma(wd, fma(0.5, wd, -(double)x[c]), acc);   // 0.5||e||^2 - x.e, exact ordering
  }
  return acc;
}

// ---- main: argmin + out_q + encodings + loss partials + histogram
__global__ __launch_bounds__(BLK) void vq_main(const float* __restrict__ in,
                                               const float* __restrict__ wt,
                                               WS* __restrict__ ws,
                                               float* __restrict__ out_q,
                                               float* __restrict__ enc) {
  __shared__ float  wtile[TE * CDIM];   // 32 KB weight tile
  __shared__ float  wn_l[EDIM];
  __shared__ int    hist[EDIM];
  __shared__ int    sIdx[BLK];
  __shared__ double lred[BLK];

  const int tid = threadIdx.x;
  for (int e = tid; e < EDIM; e += BLK) {
    wn_l[e] = ws->wnh[e];
    hist[e] = 0;
  }

  const int n = blockIdx.x * BLK + tid;     // vector index; lanes = consecutive spatial pos
  const int b = n >> 15;                    // batch
  const int s = n & (SPATIAL - 1);          // d*h*w flat
  const float* xp = in + (size_t)b * CDIM * SPATIAL + s;

  // load the 128-dim vector into registers (coalesced per channel)
  float x[CDIM];
#pragma unroll
  for (int c = 0; c < CDIM; ++c) x[c] = xp[(size_t)c * SPATIAL];

  // fp32 scoring: s_e = 0.5||e||^2 - x.e ; track top-3 values, top-2 indices
  float best = 1e30f, best2 = 1e30f, best3 = 1e30f;
  int bi = 0, bi2 = 0;

  for (int et = 0; et < EDIM; et += TE) {
    __syncthreads();
    // stage 64 weight rows into LDS (float4 global loads, coalesced)
    {
      const float4* src = (const float4*)(wt + (size_t)et * CDIM);
      float4* dst = (float4*)wtile;
#pragma unroll
      for (int i = 0; i < (TE * CDIM / 4) / BLK; ++i)
        dst[tid + i * BLK] = src[tid + i * BLK];
    }
    __syncthreads();

    for (int el = 0; el < TE; ++el) {
      const float* w = wtile + el * CDIM;   // wave-uniform LDS address -> broadcast reads
      float a0 = 0.f, a1 = 0.f, a2 = 0.f, a3 = 0.f;
#pragma unroll
      for (int c = 0; c < CDIM; c += 4) {
        float4 wv = *(const float4*)(w + c);   // ds_read_b128, conflict-free broadcast
        a0 = fmaf(wv.x, x[c + 0], a0);
        a1 = fmaf(wv.y, x[c + 1], a1);
        a2 = fmaf(wv.z, x[c + 2], a2);
        a3 = fmaf(wv.w, x[c + 3], a3);
      }
      float sc = wn_l[et + el] - ((a0 + a1) + (a2 + a3));
      // branch-free top-3 insert (strict <: first-index tie-break)
      bool lt1 = sc < best, lt2 = sc < best2, lt3 = sc < best3;
      best3 = lt2 ? best2 : (lt3 ? sc : best3);
      best2 = lt1 ? best  : (lt2 ? sc : best2);
      bi2   = lt1 ? bi    : (lt2 ? (et + el) : bi2);
      best  = lt1 ? sc : best;
      bi    = lt1 ? (et + el) : bi;
    }
  }

  // ambiguity resolution in fp64 (exact vs fp64 numpy reference ordering)
  if (best3 - best < 2e-6f) {
    // 3-way near-tie: essentially never (P~1e-6) — full exact scan
    double bd = 1e300; int bj = 0;
    for (int e = 0; e < EDIM; ++e) {
      double sc = score_f64(wt, x, e);
      if (sc < bd) { bd = sc; bj = e; }
    }
    bi = bj;
  } else if (best2 - best < 2e-6f) {
    // 2-way: exact compare of just the two candidate rows
    double s1 = score_f64(wt, x, bi);
    double s2 = score_f64(wt, x, bi2);
    if (s2 < s1 || (s2 == s1 && bi2 < bi)) bi = bi2;
  }

  atomicAdd(&hist[bi], 1);
  sIdx[tid] = bi;

  // gather quantized row: write out_q (transposed back) + fp64 loss partial
  const float* __restrict__ wq = wt + (size_t)bi * CDIM;
  float* oq = out_q + (size_t)b * CDIM * SPATIAL + s;
  double ls = 0.0;
#pragma unroll
  for (int c = 0; c < CDIM; ++c) {
    float qv = wq[c];
    double d = (double)qv - (double)x[c];
    ls = fma(d, d, ls);
    oq[(size_t)c * SPATIAL] = qv;          // coalesced per channel
  }
  lred[tid] = ls;
  __syncthreads();

  // cooperative one-hot rows: block owns rows n0..n0+255, 256 float2 per row.
  // (enc base is 8B-aligned only: byte offset (2+QELEMS)*4 % 16 == 8 -> float2)
  {
    const size_t n0 = (size_t)blockIdx.x * BLK;
    float2* e2 = (float2*)enc;
    const int col = tid;
    const int c0 = col * 2;
    for (int r = 0; r < BLK; ++r) {
      int idx = sIdx[r];
      float2 v;
      v.x = (idx == c0) ? 1.0f : 0.0f;
      v.y = (idx == c0 + 1) ? 1.0f : 0.0f;
      e2[(n0 + (size_t)r) * (EDIM / 2) + col] = v;
    }
  }

  // block loss reduction -> one double atomic
  for (int off = BLK / 2; off > 0; off >>= 1) {
    if (tid < off) lred[tid] += lred[tid + off];
    __syncthreads();
  }
  if (tid == 0) atomicAdd(&ws->lossAcc, lred[0]);

  // flush histogram
  for (int e = tid; e < EDIM; e += BLK) {
    int v = hist[e];
    if (v) atomicAdd(&ws->counts[e], v);
  }
}

// ---- finalize: loss scalar + perplexity from exact counts
__global__ __launch_bounds__(512) void vq_fin(const WS* __restrict__ ws, float* __restrict__ out) {
  __shared__ double red[EDIM];
  int t = threadIdx.x;
  double p = (double)ws->counts[t] * (1.0 / (double)NVEC);
  red[t] = p * log(p + 1e-10);
  __syncthreads();
  for (int off = 256; off > 0; off >>= 1) {
    if (t < off) red[t] += red[t + off];
    __syncthreads();
  }
  if (t == 0) {
    out[0] = (float)(1.25 * ws->lossAcc / (double)QELEMS);  // q_latent + 0.25*e_latent
    out[1 + QELEMS] = (float)exp(-red[0]);                  // perplexity
  }
}

extern "C" void kernel_launch(void* const* d_in, const int* in_sizes, int n_in,
                              void* d_out, int out_size, void* d_ws, size_t ws_size,
                              hipStream_t stream) {
  const float* in = (const float*)d_in[0];   // (8,128,32,32,32) fp32
  const float* wt = (const float*)d_in[1];   // (512,128) fp32
  float* out = (float*)d_out;
  WS* ws = (WS*)d_ws;

  float* out_q = out + 1;                    // 33,554,432 elems
  float* enc   = out + 2 + QELEMS;           // 134,217,728 elems

  hipLaunchKernelGGL(vq_pre,  dim3(1),          dim3(512), 0, stream, wt, ws);
  hipLaunchKernelGGL(vq_main, dim3(NVEC / BLK), dim3(BLK), 0, stream, in, wt, ws, out_q, enc);
  hipLaunchKernelGGL(vq_fin,  dim3(1),          dim3(512), 0, stream, ws, out);
}

// Round 3
// 1101.838 us; speedup vs baseline: 4.2841x; 2.0157x over previous
//
#include <hip/hip_runtime.h>
#include <math.h>

#define CDIM 128
#define EDIM 512
#define BLK 256
#define MT 128               // vectors per block
#define NCH 128              // embedding chunk
#define KCH 32               // k chunk
#define NVEC 262144          // 8*32*32*32
#define SPATIAL 32768
#define QELEMS 33554432LL

struct WS {
  float  wnh[EDIM];          // 0.5*||e||^2
  int    counts[EDIM];
  double lossAcc;
  double _pad;               // align wT to 16B
  float  wT[CDIM * EDIM];    // transposed weights [c][e] (optional, if ws fits)
};

// ---- pre-pass: half norms, zero accumulators, optional w transpose
__global__ __launch_bounds__(512) void vq_pre(const float* __restrict__ wt,
                                              WS* __restrict__ ws, int buildWT) {
  int t = threadIdx.x;
  const float* w = wt + (size_t)t * CDIM;
  float a0 = 0.f, a1 = 0.f, a2 = 0.f, a3 = 0.f;
#pragma unroll
  for (int c = 0; c < CDIM; c += 4) {
    a0 = fmaf(w[c + 0], w[c + 0], a0);
    a1 = fmaf(w[c + 1], w[c + 1], a1);
    a2 = fmaf(w[c + 2], w[c + 2], a2);
    a3 = fmaf(w[c + 3], w[c + 3], a3);
  }
  ws->wnh[t] = 0.5f * ((a0 + a1) + (a2 + a3));
  ws->counts[t] = 0;
  if (t == 0) ws->lossAcc = 0.0;
  if (buildWT) {
    for (int c = 0; c < CDIM; ++c) ws->wT[c * EDIM + t] = w[c];  // coalesced writes
  }
}

__device__ double score64(const float* __restrict__ in, const float* __restrict__ wt,
                          size_t xoff, int e) {
  const float* w = wt + (size_t)e * CDIM;
  double a = 0.0;
  for (int c = 0; c < CDIM; ++c) {
    double wd = (double)w[c];
    double xv = (double)in[xoff + (size_t)c * SPATIAL];
    a = fma(wd, fma(0.5, wd, -xv), a);    // 0.5||e||^2 - x.e, exact ordering
  }
  return a;
}

template <bool USEWT>
__global__ __launch_bounds__(BLK, 3) void vq_main(const float* __restrict__ in,
                                                  const float* __restrict__ wt,
                                                  WS* __restrict__ ws,
                                                  float* __restrict__ out_q,
                                                  float* __restrict__ enc) {
  // union region: GEMM tiles (32 KB) then argmin-merge arrays (42.5 KB)
  __shared__ __align__(16) char uni[43520];
  float (*xt)[MT]  = (float(*)[MT])uni;                 // [KCH][MT]
  float (*wl)[NCH] = (float(*)[NCH])(uni + KCH * MT * 4);
  float (*cb1)[17] = (float(*)[17])uni;                 // [128][17] padded (bank-safe)
  float (*cb2)[17] = (float(*)[17])(uni + 8704);
  float (*cb3)[17] = (float(*)[17])(uni + 17408);
  int   (*ci1)[17] = (int(*)[17])(uni + 26112);
  int   (*ci2)[17] = (int(*)[17])(uni + 34816);
  __shared__ float  wn_l[EDIM];
  __shared__ int    hist[EDIM];
  __shared__ int    sIdx[MT];
  __shared__ double lred[BLK];

  const int tid = threadIdx.x;
  for (int e = tid; e < EDIM; e += BLK) { wn_l[e] = ws->wnh[e]; hist[e] = 0; }

  const int n0 = blockIdx.x * MT;
  const int b  = n0 >> 15;
  const int s0 = n0 & (SPATIAL - 1);
  const size_t ibase = (size_t)b * CDIM * SPATIAL;

  const int tm = tid & 15, tn = tid >> 4;      // 16 x 16 thread grid, 8x8 tile each
  const int sg = tid & 31, sk = tid >> 5;      // staging: 32 cols x 8 rows
  const int wq8 = tid & 7, wn32 = tid >> 3;    // raw-w staging

  float acc[8][8];
  float bst1[8], bst2[8], bst3[8];
  int   bi1[8], bi2[8];
#pragma unroll
  for (int i = 0; i < 8; ++i) { bst1[i] = 1e30f; bst2[i] = 1e30f; bst3[i] = 1e30f; bi1[i] = 0; bi2[i] = 0; }

  for (int nc = 0; nc < EDIM / NCH; ++nc) {
#pragma unroll
    for (int i = 0; i < 8; ++i)
#pragma unroll
      for (int j = 0; j < 8; ++j) acc[i][j] = 0.f;

    for (int kc = 0; kc < CDIM / KCH; ++kc) {
      __syncthreads();
      // stage x tile [k][m] (coalesced float4, contiguous LDS rows)
#pragma unroll
      for (int p = 0; p < 4; ++p) {
        int k = sk + 8 * p;
        float4 v = *(const float4*)(in + ibase + (size_t)(kc * KCH + k) * SPATIAL + s0 + sg * 4);
        *(float4*)&xt[k][sg * 4] = v;
      }
      // stage w tile [k][n]
      if (USEWT) {
#pragma unroll
        for (int p = 0; p < 4; ++p) {
          int k = sk + 8 * p;
          float4 v = *(const float4*)(ws->wT + (size_t)(kc * KCH + k) * EDIM + nc * NCH + sg * 4);
          *(float4*)&wl[k][sg * 4] = v;
        }
      } else {
#pragma unroll
        for (int p = 0; p < 4; ++p) {
          int nn = wn32 + 32 * p;
          float4 v = *(const float4*)(wt + (size_t)(nc * NCH + nn) * CDIM + kc * KCH + wq8 * 4);
          wl[wq8 * 4 + 0][nn] = v.x; wl[wq8 * 4 + 1][nn] = v.y;
          wl[wq8 * 4 + 2][nn] = v.z; wl[wq8 * 4 + 3][nn] = v.w;
        }
      }
      __syncthreads();
#pragma unroll 2
      for (int k = 0; k < KCH; ++k) {
        float4 xa = *(const float4*)&xt[k][tm * 8];
        float4 xb = *(const float4*)&xt[k][tm * 8 + 4];
        float4 wa = *(const float4*)&wl[k][tn * 8];
        float4 wb = *(const float4*)&wl[k][tn * 8 + 4];
        float xf[8] = {xa.x, xa.y, xa.z, xa.w, xb.x, xb.y, xb.z, xb.w};
        float wf[8] = {wa.x, wa.y, wa.z, wa.w, wb.x, wb.y, wb.z, wb.w};
#pragma unroll
        for (int i = 0; i < 8; ++i)
#pragma unroll
          for (int j = 0; j < 8; ++j) acc[i][j] = fmaf(xf[i], wf[j], acc[i][j]);
      }
    }
    // epilogue: scores + per-thread top-3 insert (e ascending -> first-index ties)
#pragma unroll
    for (int j = 0; j < 8; ++j) {
      int e = nc * NCH + tn * 8 + j;
      float wn = wn_l[e];
#pragma unroll
      for (int i = 0; i < 8; ++i) {
        float sc = wn - acc[i][j];
        if (sc < bst1[i]) { bst3[i] = bst2[i]; bst2[i] = bst1[i]; bi2[i] = bi1[i]; bst1[i] = sc; bi1[i] = e; }
        else if (sc < bst2[i]) { bst3[i] = bst2[i]; bst2[i] = sc; bi2[i] = e; }
        else if (sc < bst3[i]) { bst3[i] = sc; }
      }
    }
  }

  __syncthreads();   // tiles dead; reuse union for merge
#pragma unroll
  for (int i = 0; i < 8; ++i) {
    int vec = tm * 8 + i;
    cb1[vec][tn] = bst1[i]; cb2[vec][tn] = bst2[i]; cb3[vec][tn] = bst3[i];
    ci1[vec][tn] = bi1[i];  ci2[vec][tn] = bi2[i];
  }
  __syncthreads();

  if (tid < MT) {
    const int vec = tid;
    float m1 = 1e30f, m2 = 1e30f, m3 = 1e30f;
    int j1 = 0x7fffffff, j2 = 0x7fffffff;
    auto ins = [&](float v, int ix) {
      bool b1 = (v < m1) || (v == m1 && ix < j1);
      bool b2 = (v < m2) || (v == m2 && ix < j2);
      if (b1)      { m3 = m2; m2 = m1; j2 = j1; m1 = v; j1 = ix; }
      else if (b2) { m3 = m2; m2 = v; j2 = ix; }
      else if (v < m3) { m3 = v; }
    };
    for (int t = 0; t < 16; ++t) {
      ins(cb1[vec][t], ci1[vec][t]);
      ins(cb2[vec][t], ci2[vec][t]);
      ins(cb3[vec][t], 0x7fffffff);   // 3rd-best can only land in slot 3 (value-only)
    }
    int bi = j1;
    const size_t xoff = ibase + s0 + vec;
    if (m3 - m1 < 2e-6f) {
      // 3-way near-tie: full exact scan (vanishingly rare)
      double bd = 1e300; int bj = 0;
      for (int e = 0; e < EDIM; ++e) {
        double a = score64(in, wt, xoff, e);
        if (a < bd) { bd = a; bj = e; }
      }
      bi = bj;
    } else if (m2 - m1 < 2e-6f) {
      double s1 = score64(in, wt, xoff, j1);
      double s2 = score64(in, wt, xoff, j2);
      if (s2 < s1 || (s2 == s1 && j2 < j1)) bi = j2;
    }
    sIdx[vec] = bi;
    atomicAdd(&hist[bi], 1);
  }
  __syncthreads();

  // out_q + loss: 256 threads = 128 vectors x 2 channel-halves
  {
    const int vec = tid & (MT - 1);
    const int half = tid >> 7;
    const int bi = sIdx[vec];
    const float* wq2 = wt + (size_t)bi * CDIM;
    const size_t base = ibase + s0 + vec;
    double ls = 0.0;
#pragma unroll 4
    for (int c = half * 64; c < half * 64 + 64; ++c) {
      float xv = in[base + (size_t)c * SPATIAL];
      float qv = wq2[c];
      out_q[base + (size_t)c * SPATIAL] = qv;     // coalesced (lanes = consecutive s)
      double d = (double)qv - (double)xv;
      ls = fma(d, d, ls);
    }
    lred[tid] = ls;
  }
  __syncthreads();
  for (int off = BLK / 2; off > 0; off >>= 1) {
    if (tid < off) lred[tid] += lred[tid + off];
    __syncthreads();
  }
  if (tid == 0) atomicAdd(&ws->lossAcc, lred[0]);

  // encodings: 128 one-hot rows, 256 float2 columns (enc base is 8B-aligned)
  {
    float2* e2 = (float2*)enc;
    const size_t r0 = (size_t)blockIdx.x * MT;
    const int c0 = tid * 2;
    for (int r = 0; r < MT; ++r) {
      int idx = sIdx[r];
      float2 v;
      v.x = (idx == c0) ? 1.0f : 0.0f;
      v.y = (idx == c0 + 1) ? 1.0f : 0.0f;
      e2[(r0 + (size_t)r) * (EDIM / 2) + tid] = v;
    }
  }

  for (int e = tid; e < EDIM; e += BLK) {
    int v = hist[e];
    if (v) atomicAdd(&ws->counts[e], v);
  }
}

// ---- finalize
__global__ __launch_bounds__(512) void vq_fin(const WS* __restrict__ ws, float* __restrict__ out) {
  __shared__ double red[EDIM];
  int t = threadIdx.x;
  double p = (double)ws->counts[t] * (1.0 / (double)NVEC);
  red[t] = p * log(p + 1e-10);
  __syncthreads();
  for (int off = 256; off > 0; off >>= 1) {
    if (t < off) red[t] += red[t + off];
    __syncthreads();
  }
  if (t == 0) {
    out[0] = (float)(1.25 * ws->lossAcc / (double)QELEMS);
    out[1 + QELEMS] = (float)exp(-red[0]);
  }
}

extern "C" void kernel_launch(void* const* d_in, const int* in_sizes, int n_in,
                              void* d_out, int out_size, void* d_ws, size_t ws_size,
                              hipStream_t stream) {
  const float* in = (const float*)d_in[0];
  const float* wt = (const float*)d_in[1];
  float* out = (float*)d_out;
  WS* ws = (WS*)d_ws;

  float* out_q = out + 1;
  float* enc   = out + 2 + QELEMS;

  const bool useWT = (ws_size >= sizeof(WS));
  vq_pre<<<dim3(1), dim3(512), 0, stream>>>(wt, ws, useWT ? 1 : 0);
  if (useWT)
    vq_main<true><<<dim3(NVEC / MT), dim3(BLK), 0, stream>>>(in, wt, ws, out_q, enc);
  else
    vq_main<false><<<dim3(NVEC / MT), dim3(BLK), 0, stream>>>(in, wt, ws, out_q, enc);
  vq_fin<<<dim3(1), dim3(512), 0, stream>>>(ws, out);
}